// Round 5
// baseline (48.567 us; speedup 1.0000x reference)
//
#include <hip/hip_runtime.h>

// Thresholded MSE == plain MSE (all branches compute (x-y)^2).
// Two-pass deterministic reduction.
// R4 experiment: input footprint (268.4 MB) is ~exactly L3 capacity (256 MiB);
// FETCH_SIZE showed classic cyclic-thrash (50% L3 retention). Mark the tail
// 32 MB of the stream non-temporal (evict-first) so the remaining 236 MB
// stays L3-resident across graph replays -> HBM fetch should drop to ~32 MB.
//   K1: grid-stride float4 loads, cached region then nt region -> wave
//       shuffle reduce -> LDS cross-wave reduce -> partial per block in d_ws.
//   K2: one wave (64 threads) reduces 2048 partials, writes mean.
// (Fused last-block variant regressed 2.3x: 2048 device-scope fences. Keep 2 kernels.)

#define BLOCKS 2048
#define THREADS 256

typedef float f32x4 __attribute__((ext_vector_type(4)));

__global__ __launch_bounds__(THREADS) void mse_partial_kernel(
    const float* __restrict__ pred, const float* __restrict__ lab,
    float* __restrict__ partials, int n_cut /* cached vec4s */,
    int n_vec /* total vec4s = N/4 */) {
    int tid = blockIdx.x * blockDim.x + threadIdx.x;
    int stride = gridDim.x * blockDim.x;

    const f32x4* p4 = reinterpret_cast<const f32x4*>(pred);
    const f32x4* l4 = reinterpret_cast<const f32x4*>(lab);

    float acc = 0.0f;

    // cached region [0, n_cut): stays L3-resident across replays
    for (int i = tid; i < n_cut; i += stride) {
        f32x4 p = p4[i];
        f32x4 l = l4[i];
        float d0 = p.x - l.x;
        float d1 = p.y - l.y;
        float d2 = p.z - l.z;
        float d3 = p.w - l.w;
        acc += d0 * d0 + d1 * d1 + d2 * d2 + d3 * d3;
    }

    // nt region [n_cut, n_vec): evict-first, sacrificed to protect the rest
    for (int i = n_cut + tid; i < n_vec; i += stride) {
        f32x4 p = __builtin_nontemporal_load(&p4[i]);
        f32x4 l = __builtin_nontemporal_load(&l4[i]);
        float d0 = p.x - l.x;
        float d1 = p.y - l.y;
        float d2 = p.z - l.z;
        float d3 = p.w - l.w;
        acc += d0 * d0 + d1 * d1 + d2 * d2 + d3 * d3;
    }

    // wave64 reduce
    #pragma unroll
    for (int off = 32; off > 0; off >>= 1)
        acc += __shfl_down(acc, off, 64);

    // cross-wave reduce via LDS (4 waves per 256-thread block)
    __shared__ float wsum[THREADS / 64];
    int lane = threadIdx.x & 63;
    int wave = threadIdx.x >> 6;
    if (lane == 0) wsum[wave] = acc;
    __syncthreads();
    if (threadIdx.x == 0) {
        partials[blockIdx.x] = wsum[0] + wsum[1] + wsum[2] + wsum[3];
    }
}

__global__ __launch_bounds__(64) void mse_final_kernel(
    const float* __restrict__ partials, float* __restrict__ out,
    float inv_n) {
    // one wave, no LDS, no __syncthreads
    const f32x4* p4 = reinterpret_cast<const f32x4*>(partials);
    float acc = 0.0f;
    #pragma unroll
    for (int j = 0; j < BLOCKS / 4 / 64; ++j) {  // 8 float4 per lane
        f32x4 v = p4[j * 64 + threadIdx.x];
        acc += (v.x + v.y) + (v.z + v.w);
    }
    #pragma unroll
    for (int off = 32; off > 0; off >>= 1)
        acc += __shfl_down(acc, off, 64);
    if (threadIdx.x == 0) out[0] = acc * inv_n;
}

extern "C" void kernel_launch(void* const* d_in, const int* in_sizes, int n_in,
                              void* d_out, int out_size, void* d_ws, size_t ws_size,
                              hipStream_t stream) {
    const float* pred = (const float*)d_in[0];
    const float* lab  = (const float*)d_in[1];
    float* out = (float*)d_out;
    float* partials = (float*)d_ws;  // BLOCKS floats (8 KB)

    int n = in_sizes[0];
    int n_vec = n / 4;                   // 8388608 vec4s
    int n_cut = n_vec - (1 << 20);       // bypass 1M vec4s x 2 arrays x 16B = 32 MB

    mse_partial_kernel<<<BLOCKS, THREADS, 0, stream>>>(pred, lab, partials, n_cut, n_vec);
    mse_final_kernel<<<1, 64, 0, stream>>>(partials, out, 1.0f / (float)n);
}

// Round 6
// 47.325 us; speedup vs baseline: 1.0262x; 1.0262x over previous
//
#include <hip/hip_runtime.h>

// Thresholded MSE == plain MSE (all branches compute (x-y)^2).
// Two-pass deterministic reduction — FINAL form (R3 best: 47.07 us).
// Negative results recorded:
//   - fused last-block + device fences: 2.3x regression (L2 trashed)
//   - x4 unroll / more ILP: neutral (memory system already saturated)
//   - nontemporal tail to protect L3 residency: FETCH_SIZE unchanged
//     (nt hint does not steer Infinity Cache replacement on gfx950)
// Main dispatch ~44us for 268.4MB = ~6.1 TB/s app BW = ~97% of the
// 6.29 TB/s measured copy ceiling -> memory roofline.

#define BLOCKS 2048
#define THREADS 256

__global__ __launch_bounds__(THREADS) void mse_partial_kernel(
    const float* __restrict__ pred, const float* __restrict__ lab,
    float* __restrict__ partials, int n_vec /* = N/4 */) {
    int tid = blockIdx.x * blockDim.x + threadIdx.x;
    int stride = gridDim.x * blockDim.x;

    const float4* p4 = reinterpret_cast<const float4*>(pred);
    const float4* l4 = reinterpret_cast<const float4*>(lab);

    float acc = 0.0f;
    for (int i = tid; i < n_vec; i += stride) {
        float4 p = p4[i];
        float4 l = l4[i];
        float d0 = p.x - l.x;
        float d1 = p.y - l.y;
        float d2 = p.z - l.z;
        float d3 = p.w - l.w;
        acc += d0 * d0 + d1 * d1 + d2 * d2 + d3 * d3;
    }

    // wave64 reduce
    #pragma unroll
    for (int off = 32; off > 0; off >>= 1)
        acc += __shfl_down(acc, off, 64);

    // cross-wave reduce via LDS (4 waves per 256-thread block)
    __shared__ float wsum[THREADS / 64];
    int lane = threadIdx.x & 63;
    int wave = threadIdx.x >> 6;
    if (lane == 0) wsum[wave] = acc;
    __syncthreads();
    if (threadIdx.x == 0) {
        partials[blockIdx.x] = wsum[0] + wsum[1] + wsum[2] + wsum[3];
    }
}

__global__ __launch_bounds__(64) void mse_final_kernel(
    const float* __restrict__ partials, float* __restrict__ out,
    float inv_n) {
    // one wave, no LDS, no __syncthreads
    const float4* p4 = reinterpret_cast<const float4*>(partials);
    float acc = 0.0f;
    #pragma unroll
    for (int j = 0; j < BLOCKS / 4 / 64; ++j) {  // 8 float4 per lane
        float4 v = p4[j * 64 + threadIdx.x];
        acc += (v.x + v.y) + (v.z + v.w);
    }
    #pragma unroll
    for (int off = 32; off > 0; off >>= 1)
        acc += __shfl_down(acc, off, 64);
    if (threadIdx.x == 0) out[0] = acc * inv_n;
}

extern "C" void kernel_launch(void* const* d_in, const int* in_sizes, int n_in,
                              void* d_out, int out_size, void* d_ws, size_t ws_size,
                              hipStream_t stream) {
    const float* pred = (const float*)d_in[0];
    const float* lab  = (const float*)d_in[1];
    float* out = (float*)d_out;
    float* partials = (float*)d_ws;  // BLOCKS floats (8 KB)

    int n = in_sizes[0];
    int n_vec = n / 4;  // N = 33554432, divisible by 4

    mse_partial_kernel<<<BLOCKS, THREADS, 0, stream>>>(pred, lab, partials, n_vec);
    mse_final_kernel<<<1, 64, 0, stream>>>(partials, out, 1.0f / (float)n);
}